// Round 2
// baseline (1121.844 us; speedup 1.0000x reference)
//
#include <hip/hip_runtime.h>
#include <hip/hip_bf16.h>

#define NNODES 50000
#define NEDGES 1600000
#define F_IN   160
#define NHEAD  8
#define NCH    8
#define HC     64
#define NGRAPH 64
#define NEG_SLOPE 0.2f

// ---------------- CSR build ----------------

__global__ void hist_kernel(const int* __restrict__ dst, int* __restrict__ cnt, int E) {
    int e = blockIdx.x * blockDim.x + threadIdx.x;
    if (e < E) atomicAdd(&cnt[dst[e]], 1);
}

// single block, 1024 threads: row_ptr[i+1] = inclusive_scan(deg[i] + 1)  (+1 = self loop)
__global__ void scan_kernel(const int* __restrict__ deg, int* __restrict__ row_ptr, int N) {
    __shared__ int sdata[1024];
    int tid = threadIdx.x;
    if (tid == 0) row_ptr[0] = 0;
    int offset = 0;
    for (int base = 0; base < N; base += 1024) {
        int i = base + tid;
        int v = (i < N) ? (deg[i] + 1) : 0;
        sdata[tid] = v;
        __syncthreads();
        for (int d = 1; d < 1024; d <<= 1) {
            int t = (tid >= d) ? sdata[tid - d] : 0;
            __syncthreads();
            sdata[tid] += t;
            __syncthreads();
        }
        if (i < N) row_ptr[i + 1] = offset + sdata[tid];
        offset += sdata[1023];
        __syncthreads();
    }
}

__global__ void scatter_kernel(const int* __restrict__ ei, const int* __restrict__ row_ptr,
                               int* __restrict__ fill, int* __restrict__ csr_src, int E, int N) {
    int i = blockIdx.x * blockDim.x + threadIdx.x;
    if (i < E) {
        int s = ei[i];
        int d = ei[E + i];
        int pos = row_ptr[d] + atomicAdd(&fill[d], 1);
        csr_src[pos] = s;
    } else if (i < E + N) {
        int n = i - E;
        int pos = row_ptr[n] + atomicAdd(&fill[n], 1);
        csr_src[pos] = n;
    }
}

// ---------------- GEMM + alpha ----------------
// block = 256 threads = 4 nodes x 64 lanes. h = in @ W  (no bias: bias is added post-aggregation)
// alpha_src[n,h] = sum_c h[n,h,c]*a_src[h,c] ; same for dst.
template <int K>
__global__ void gemm_alpha_kernel(const float* __restrict__ in, const float* __restrict__ W,
                                  const float* __restrict__ aS, const float* __restrict__ aD,
                                  float* __restrict__ h_out, float* __restrict__ alpha_s,
                                  float* __restrict__ alpha_d, int N) {
    __shared__ float xs[4][K];
    int tid = threadIdx.x;
    int nodeBase = blockIdx.x * 4;
    for (int idx = tid; idx < 4 * K; idx += 256) {
        int r = idx / K, c = idx - r * K;
        int n = nodeBase + r;
        xs[r][c] = (n < N) ? in[n * K + c] : 0.f;
    }
    __syncthreads();
    int r = tid >> 6, lane = tid & 63;
    int node = nodeBase + r;
    if (node >= N) return;

    float acc = 0.f;
#pragma unroll
    for (int k = 0; k < K; k++) acc = fmaf(xs[r][k], W[k * HC + lane], acc);

    h_out[node * HC + lane] = acc;

    // per-head reduction over c = lane&7
    float vs = acc * aS[lane];
    float vd = acc * aD[lane];
    vs += __shfl_xor(vs, 1); vs += __shfl_xor(vs, 2); vs += __shfl_xor(vs, 4);
    vd += __shfl_xor(vd, 1); vd += __shfl_xor(vd, 2); vd += __shfl_xor(vd, 4);
    if ((lane & 7) == 0) {
        int head = lane >> 3;
        alpha_s[node * NHEAD + head] = vs;
        alpha_d[node * NHEAD + head] = vd;
    }
}

// ---------------- Aggregation (one wave per dst node, online softmax) ----------------
__global__ void agg_kernel(const float* __restrict__ h, const float* __restrict__ as_,
                           const float* __restrict__ ad_, const int* __restrict__ rowp,
                           const int* __restrict__ csr, const float* __restrict__ bias,
                           float* __restrict__ out, int N) {
    int tid = threadIdx.x;
    int node = blockIdx.x * 4 + (tid >> 6);
    if (node >= N) return;
    int lane = tid & 63;
    int head = lane >> 3;

    int beg = rowp[node], end = rowp[node + 1];
    float adn = ad_[node * NHEAD + head];

    float m = -1e30f, num = 0.f, den = 0.f;
    for (int i = beg; i < end; i++) {
        int s = csr[i];
        float e = as_[s * NHEAD + head] + adn;
        e = (e > 0.f) ? e : NEG_SLOPE * e;
        float mn = fmaxf(m, e);
        float scale = __expf(m - mn);
        float w = __expf(e - mn);
        float hv = h[s * HC + lane];
        num = num * scale + w * hv;
        den = den * scale + w;
        m = mn;
    }
    float o = num / (den + 1e-16f) + bias[lane];
    out[node * HC + lane] = (o > 0.f) ? o : (__expf(o) - 1.f);
}

// ---------------- Pooling (batch is sorted) ----------------
#define POOL_CHUNK 512
__global__ void pool_kernel(const float* __restrict__ h, const int* __restrict__ batch,
                            float* __restrict__ pooled, float* __restrict__ gcnt, int N) {
    int lane = threadIdx.x;  // 64
    int start = blockIdx.x * POOL_CHUNK;
    if (start >= N) return;
    int end = start + POOL_CHUNK; if (end > N) end = N;

    int cur = batch[start];
    float acc = 0.f;
    int run = 0;
    for (int n = start; n < end; n++) {
        int g = batch[n];
        if (g != cur) {
            atomicAdd(&pooled[cur * HC + lane], acc);
            if (lane == 0) atomicAdd(&gcnt[cur], (float)run);
            cur = g; acc = 0.f; run = 0;
        }
        acc += h[n * HC + lane];
        run++;
    }
    atomicAdd(&pooled[cur * HC + lane], acc);
    if (lane == 0) atomicAdd(&gcnt[cur], (float)run);
}

// ---------------- Head: mean, linear, log_softmax ----------------
__global__ void head_kernel(const float* __restrict__ pooled, const float* __restrict__ gcnt,
                            const float* __restrict__ Wlin, const float* __restrict__ blin,
                            float* __restrict__ out) {
    int g = threadIdx.x;
    if (g >= NGRAPH) return;
    float c = fmaxf(gcnt[g], 1.f);
    float l0 = blin[0], l1 = blin[1];
    for (int k = 0; k < HC; k++) {
        float p = pooled[g * HC + k] / c;
        l0 = fmaf(p, Wlin[k * 2 + 0], l0);
        l1 = fmaf(p, Wlin[k * 2 + 1], l1);
    }
    float mx = fmaxf(l0, l1);
    float lse = mx + logf(expf(l0 - mx) + expf(l1 - mx));
    out[g * 2 + 0] = l0 - lse;
    out[g * 2 + 1] = l1 - lse;
}

// ---------------- launch ----------------
extern "C" void kernel_launch(void* const* d_in, const int* in_sizes, int n_in,
                              void* d_out, int out_size, void* d_ws, size_t ws_size,
                              hipStream_t stream) {
    const float* x    = (const float*)d_in[0];
    const int*   ei   = (const int*)d_in[1];
    const int*   batch= (const int*)d_in[2];
    const float* W1   = (const float*)d_in[3];
    const float* a1s  = (const float*)d_in[4];
    const float* a1d  = (const float*)d_in[5];
    const float* b1   = (const float*)d_in[6];
    const float* W2   = (const float*)d_in[7];
    const float* a2s  = (const float*)d_in[8];
    const float* a2d  = (const float*)d_in[9];
    const float* b2   = (const float*)d_in[10];
    const float* W3   = (const float*)d_in[11];
    const float* a3s  = (const float*)d_in[12];
    const float* a3d  = (const float*)d_in[13];
    const float* b3   = (const float*)d_in[14];
    const float* Wlin = (const float*)d_in[15];
    const float* blin = (const float*)d_in[16];
    float* out = (float*)d_out;

    const int N = NNODES, E = NEDGES, Et = E + N;

    // workspace layout
    char* ws = (char*)d_ws;
    size_t off = 0;
    auto alloc = [&](size_t bytes) { char* p = ws + off; off += (bytes + 255) & ~(size_t)255; return p; };
    int*   row_ptr = (int*)alloc((N + 1) * sizeof(int));
    int*   fill    = (int*)alloc(N * sizeof(int));
    int*   csr_src = (int*)alloc((size_t)Et * sizeof(int));
    float* as_     = (float*)alloc((size_t)N * NHEAD * sizeof(float));
    float* ad_     = (float*)alloc((size_t)N * NHEAD * sizeof(float));
    float* hA      = (float*)alloc((size_t)N * HC * sizeof(float));
    float* hB      = (float*)alloc((size_t)N * HC * sizeof(float));
    float* pooled  = (float*)alloc(NGRAPH * HC * sizeof(float));
    float* gcnt    = (float*)alloc(NGRAPH * sizeof(float));

    // ---- CSR build ----
    hipMemsetAsync(fill, 0, N * sizeof(int), stream);
    hist_kernel<<<(E + 255) / 256, 256, 0, stream>>>(ei + E, fill, E);
    scan_kernel<<<1, 1024, 0, stream>>>(fill, row_ptr, N);
    hipMemsetAsync(fill, 0, N * sizeof(int), stream);
    scatter_kernel<<<(Et + 255) / 256, 256, 0, stream>>>(ei, row_ptr, fill, csr_src, E, N);

    int nodeBlocks = (N + 3) / 4;

    // ---- Layer 1 ----
    gemm_alpha_kernel<F_IN><<<nodeBlocks, 256, 0, stream>>>(x, W1, a1s, a1d, hA, as_, ad_, N);
    agg_kernel<<<nodeBlocks, 256, 0, stream>>>(hA, as_, ad_, row_ptr, csr_src, b1, hB, N);

    // ---- Layer 2 ----
    gemm_alpha_kernel<HC><<<nodeBlocks, 256, 0, stream>>>(hB, W2, a2s, a2d, hA, as_, ad_, N);
    agg_kernel<<<nodeBlocks, 256, 0, stream>>>(hA, as_, ad_, row_ptr, csr_src, b2, hB, N);

    // ---- Layer 3 ----
    gemm_alpha_kernel<HC><<<nodeBlocks, 256, 0, stream>>>(hB, W3, a3s, a3d, hA, as_, ad_, N);
    agg_kernel<<<nodeBlocks, 256, 0, stream>>>(hA, as_, ad_, row_ptr, csr_src, b3, hB, N);

    // ---- Pool + head ----
    hipMemsetAsync(pooled, 0, NGRAPH * HC * sizeof(float), stream);
    hipMemsetAsync(gcnt, 0, NGRAPH * sizeof(float), stream);
    pool_kernel<<<(N + POOL_CHUNK - 1) / POOL_CHUNK, 64, 0, stream>>>(hB, batch, pooled, gcnt, N);
    head_kernel<<<1, 64, 0, stream>>>(pooled, gcnt, Wlin, blin, out);
}

// Round 3
// 769.592 us; speedup vs baseline: 1.4577x; 1.4577x over previous
//
#include <hip/hip_runtime.h>
#include <hip/hip_bf16.h>

#define NNODES 50000
#define NEDGES 1600000
#define F_IN   160
#define NHEAD  8
#define NCH    8
#define HC     64
#define NGRAPH 64
#define NEG_SLOPE 0.2f

// ---------------- CSR build ----------------

__global__ void hist_kernel(const int* __restrict__ dst, int* __restrict__ cnt, int E) {
    int e = blockIdx.x * blockDim.x + threadIdx.x;
    if (e < E) atomicAdd(&cnt[dst[e]], 1);
}

// single block, 1024 threads, one pass: each thread scans a contiguous chunk
// sequentially (carry in register), then one 1024-wide LDS scan of chunk totals.
__global__ void scan_kernel(const int* __restrict__ deg, int* __restrict__ row_ptr, int N) {
    __shared__ int tot[1024];
    int tid = threadIdx.x;
    const int CH = (N + 1023) / 1024;
    int b0 = tid * CH;
    int b1 = b0 + CH; if (b1 > N) b1 = N;
    int sum = 0;
    for (int i = b0; i < b1; i++) sum += deg[i] + 1;   // +1 = self loop
    tot[tid] = sum;
    __syncthreads();
    for (int d = 1; d < 1024; d <<= 1) {
        int t = (tid >= d) ? tot[tid - d] : 0;
        __syncthreads();
        tot[tid] += t;
        __syncthreads();
    }
    int run = tot[tid] - sum;  // exclusive prefix of this chunk
    if (tid == 0) row_ptr[0] = 0;
    for (int i = b0; i < b1; i++) {
        run += deg[i] + 1;
        row_ptr[i + 1] = run;
    }
}

__global__ void scatter_kernel(const int* __restrict__ ei, const int* __restrict__ row_ptr,
                               int* __restrict__ fill, int* __restrict__ csr_src, int E, int N) {
    int i = blockIdx.x * blockDim.x + threadIdx.x;
    if (i < E) {
        int s = ei[i];
        int d = ei[E + i];
        int pos = row_ptr[d] + atomicAdd(&fill[d], 1);
        csr_src[pos] = s;
    } else if (i < E + N) {
        int n = i - E;
        int pos = row_ptr[n] + atomicAdd(&fill[n], 1);
        csr_src[pos] = n;
    }
}

// ---------------- GEMM + alpha ----------------
template <int K>
__global__ void gemm_alpha_kernel(const float* __restrict__ in, const float* __restrict__ W,
                                  const float* __restrict__ aS, const float* __restrict__ aD,
                                  float* __restrict__ h_out, float* __restrict__ alpha_s,
                                  float* __restrict__ alpha_d, int N) {
    __shared__ float xs[4][K];
    int tid = threadIdx.x;
    int nodeBase = blockIdx.x * 4;
    for (int idx = tid; idx < 4 * K; idx += 256) {
        int r = idx / K, c = idx - r * K;
        int n = nodeBase + r;
        xs[r][c] = (n < N) ? in[n * K + c] : 0.f;
    }
    __syncthreads();
    int r = tid >> 6, lane = tid & 63;
    int node = nodeBase + r;
    if (node >= N) return;

    float acc = 0.f;
#pragma unroll
    for (int k = 0; k < K; k++) acc = fmaf(xs[r][k], W[k * HC + lane], acc);

    h_out[node * HC + lane] = acc;

    float vs = acc * aS[lane];
    float vd = acc * aD[lane];
    vs += __shfl_xor(vs, 1); vs += __shfl_xor(vs, 2); vs += __shfl_xor(vs, 4);
    vd += __shfl_xor(vd, 1); vd += __shfl_xor(vd, 2); vd += __shfl_xor(vd, 4);
    if ((lane & 7) == 0) {
        int head = lane >> 3;
        alpha_s[node * NHEAD + head] = vs;
        alpha_d[node * NHEAD + head] = vd;
    }
}

// ---------------- Aggregation: 2-pass per node, no serial dependence ----------------
// Pass 1: per-head max, lanes parallelize 8x over edges (lane = edge_off*8 + head).
// Pass 2: fixed-max weighted sum, lanes = 64 channels, 4-wide unroll -> independent gathers.
__global__ void agg_kernel(const float* __restrict__ h, const float* __restrict__ as_,
                           const float* __restrict__ ad_, const int* __restrict__ rowp,
                           const int* __restrict__ csr, const float* __restrict__ bias,
                           float* __restrict__ out, int N) {
    int tid = threadIdx.x;
    int node = blockIdx.x * 4 + (tid >> 6);
    if (node >= N) return;
    int lane = tid & 63;

    int beg = rowp[node], end = rowp[node + 1];
    int deg = end - beg;

    // ---- pass 1: max per head
    int h1 = lane & 7;      // head handled by this lane in pass 1
    int eo = lane >> 3;     // edge offset (0..7)
    float adn1 = ad_[node * NHEAD + h1];
    float m = -1e30f;
    for (int j = eo; j < deg; j += 8) {
        int s = csr[beg + j];
        float e = as_[s * NHEAD + h1] + adn1;
        e = (e > 0.f) ? e : NEG_SLOPE * e;
        m = fmaxf(m, e);
    }
    m = fmaxf(m, __shfl_xor(m, 8));
    m = fmaxf(m, __shfl_xor(m, 16));
    m = fmaxf(m, __shfl_xor(m, 32));
    // lane L now holds max for head L&7; redistribute to pass-2 layout head = lane>>3
    int head = lane >> 3;
    m = __shfl(m, head);
    float adn = __shfl(adn1, head);

    // ---- pass 2: weighted sum (independent iterations, 4-wide)
    float num0 = 0.f, den0 = 0.f, num1 = 0.f, den1 = 0.f;
    float num2 = 0.f, den2 = 0.f, num3 = 0.f, den3 = 0.f;
    int i = beg;
    for (; i + 3 < end; i += 4) {
        int s0 = csr[i], s1 = csr[i + 1], s2 = csr[i + 2], s3 = csr[i + 3];
        float e0 = as_[s0 * NHEAD + head] + adn;
        float e1 = as_[s1 * NHEAD + head] + adn;
        float e2 = as_[s2 * NHEAD + head] + adn;
        float e3 = as_[s3 * NHEAD + head] + adn;
        e0 = (e0 > 0.f) ? e0 : NEG_SLOPE * e0;
        e1 = (e1 > 0.f) ? e1 : NEG_SLOPE * e1;
        e2 = (e2 > 0.f) ? e2 : NEG_SLOPE * e2;
        e3 = (e3 > 0.f) ? e3 : NEG_SLOPE * e3;
        float w0 = __expf(e0 - m), w1 = __expf(e1 - m);
        float w2 = __expf(e2 - m), w3 = __expf(e3 - m);
        float hv0 = h[s0 * HC + lane], hv1 = h[s1 * HC + lane];
        float hv2 = h[s2 * HC + lane], hv3 = h[s3 * HC + lane];
        num0 = fmaf(w0, hv0, num0); den0 += w0;
        num1 = fmaf(w1, hv1, num1); den1 += w1;
        num2 = fmaf(w2, hv2, num2); den2 += w2;
        num3 = fmaf(w3, hv3, num3); den3 += w3;
    }
    for (; i < end; i++) {
        int s0 = csr[i];
        float e0 = as_[s0 * NHEAD + head] + adn;
        e0 = (e0 > 0.f) ? e0 : NEG_SLOPE * e0;
        float w0 = __expf(e0 - m);
        num0 = fmaf(w0, h[s0 * HC + lane], num0); den0 += w0;
    }
    float num = (num0 + num1) + (num2 + num3);
    float den = (den0 + den1) + (den2 + den3);
    float o = num / (den + 1e-16f) + bias[lane];
    out[node * HC + lane] = (o > 0.f) ? o : (__expf(o) - 1.f);
}

// ---------------- Pooling: one block per graph (batch is sorted), atomic-free ----------------
__global__ void pool_kernel(const float* __restrict__ h, const int* __restrict__ batch,
                            float* __restrict__ pooled, float* __restrict__ gcnt, int N) {
    int g = blockIdx.x;            // 64 blocks
    int tid = threadIdx.x;         // 256 = 4 waves x 64 lanes
    int lane = tid & 63, w = tid >> 6;
    int lo = 0, hi = N;
    while (lo < hi) { int mid = (lo + hi) >> 1; if (batch[mid] < g) lo = mid + 1; else hi = mid; }
    int start = lo;
    hi = N;
    while (lo < hi) { int mid = (lo + hi) >> 1; if (batch[mid] < g + 1) lo = mid + 1; else hi = mid; }
    int end = lo;

    float acc = 0.f;
    for (int n = start + w; n < end; n += 4) acc += h[n * HC + lane];
    __shared__ float red[4][HC];
    red[w][lane] = acc;
    __syncthreads();
    if (w == 0) {
        float s = (red[0][lane] + red[1][lane]) + (red[2][lane] + red[3][lane]);
        pooled[g * HC + lane] = s;
        if (lane == 0) gcnt[g] = (float)(end - start);
    }
}

// ---------------- Head: mean, linear, log_softmax ----------------
__global__ void head_kernel(const float* __restrict__ pooled, const float* __restrict__ gcnt,
                            const float* __restrict__ Wlin, const float* __restrict__ blin,
                            float* __restrict__ out) {
    int g = threadIdx.x;
    if (g >= NGRAPH) return;
    float c = fmaxf(gcnt[g], 1.f);
    float l0 = blin[0], l1 = blin[1];
    for (int k = 0; k < HC; k++) {
        float p = pooled[g * HC + k] / c;
        l0 = fmaf(p, Wlin[k * 2 + 0], l0);
        l1 = fmaf(p, Wlin[k * 2 + 1], l1);
    }
    float mx = fmaxf(l0, l1);
    float lse = mx + logf(expf(l0 - mx) + expf(l1 - mx));
    out[g * 2 + 0] = l0 - lse;
    out[g * 2 + 1] = l1 - lse;
}

// ---------------- launch ----------------
extern "C" void kernel_launch(void* const* d_in, const int* in_sizes, int n_in,
                              void* d_out, int out_size, void* d_ws, size_t ws_size,
                              hipStream_t stream) {
    const float* x    = (const float*)d_in[0];
    const int*   ei   = (const int*)d_in[1];
    const int*   batch= (const int*)d_in[2];
    const float* W1   = (const float*)d_in[3];
    const float* a1s  = (const float*)d_in[4];
    const float* a1d  = (const float*)d_in[5];
    const float* b1   = (const float*)d_in[6];
    const float* W2   = (const float*)d_in[7];
    const float* a2s  = (const float*)d_in[8];
    const float* a2d  = (const float*)d_in[9];
    const float* b2   = (const float*)d_in[10];
    const float* W3   = (const float*)d_in[11];
    const float* a3s  = (const float*)d_in[12];
    const float* a3d  = (const float*)d_in[13];
    const float* b3   = (const float*)d_in[14];
    const float* Wlin = (const float*)d_in[15];
    const float* blin = (const float*)d_in[16];
    float* out = (float*)d_out;

    const int N = NNODES, E = NEDGES, Et = E + N;

    char* ws = (char*)d_ws;
    size_t off = 0;
    auto alloc = [&](size_t bytes) { char* p = ws + off; off += (bytes + 255) & ~(size_t)255; return p; };
    int*   row_ptr = (int*)alloc((N + 1) * sizeof(int));
    int*   fill    = (int*)alloc(N * sizeof(int));
    int*   csr_src = (int*)alloc((size_t)Et * sizeof(int));
    float* as_     = (float*)alloc((size_t)N * NHEAD * sizeof(float));
    float* ad_     = (float*)alloc((size_t)N * NHEAD * sizeof(float));
    float* hA      = (float*)alloc((size_t)N * HC * sizeof(float));
    float* hB      = (float*)alloc((size_t)N * HC * sizeof(float));
    float* pooled  = (float*)alloc(NGRAPH * HC * sizeof(float));
    float* gcnt    = (float*)alloc(NGRAPH * sizeof(float));

    // ---- CSR build ----
    hipMemsetAsync(fill, 0, N * sizeof(int), stream);
    hist_kernel<<<(E + 255) / 256, 256, 0, stream>>>(ei + E, fill, E);
    scan_kernel<<<1, 1024, 0, stream>>>(fill, row_ptr, N);
    hipMemsetAsync(fill, 0, N * sizeof(int), stream);
    scatter_kernel<<<(Et + 255) / 256, 256, 0, stream>>>(ei, row_ptr, fill, csr_src, E, N);

    int nodeBlocks = (N + 3) / 4;

    // ---- Layer 1 ----
    gemm_alpha_kernel<F_IN><<<nodeBlocks, 256, 0, stream>>>(x, W1, a1s, a1d, hA, as_, ad_, N);
    agg_kernel<<<nodeBlocks, 256, 0, stream>>>(hA, as_, ad_, row_ptr, csr_src, b1, hB, N);

    // ---- Layer 2 ----
    gemm_alpha_kernel<HC><<<nodeBlocks, 256, 0, stream>>>(hB, W2, a2s, a2d, hA, as_, ad_, N);
    agg_kernel<<<nodeBlocks, 256, 0, stream>>>(hA, as_, ad_, row_ptr, csr_src, b2, hB, N);

    // ---- Layer 3 ----
    gemm_alpha_kernel<HC><<<nodeBlocks, 256, 0, stream>>>(hB, W3, a3s, a3d, hA, as_, ad_, N);
    agg_kernel<<<nodeBlocks, 256, 0, stream>>>(hA, as_, ad_, row_ptr, csr_src, b3, hB, N);

    // ---- Pool + head ----
    pool_kernel<<<NGRAPH, 256, 0, stream>>>(hB, batch, pooled, gcnt, N);
    head_kernel<<<1, 64, 0, stream>>>(pooled, gcnt, Wlin, blin, out);
}